// Round 4
// baseline (459.535 us; speedup 1.0000x reference)
//
#include <hip/hip_runtime.h>
#include <hip/hip_bf16.h>

#define NN 8192
#define DD 128

typedef __attribute__((ext_vector_type(4))) float f32x4;
typedef __attribute__((ext_vector_type(8))) short s16x8;
typedef __attribute__((ext_vector_type(4))) short s16x4;

template <typename T>
__device__ inline T ntload(const T* p) { return __builtin_nontemporal_load(p); }

__device__ inline short bfbits(float f) {
    unsigned u = __builtin_bit_cast(unsigned, f);
    u += 0x7fffu + ((u >> 16) & 1u);
    return (short)(u >> 16);
}

__device__ inline s16x4 cvt4(f32x4 a) {
    s16x4 r;
    r[0] = bfbits(a[0]); r[1] = bfbits(a[1]); r[2] = bfbits(a[2]); r[3] = bfbits(a[3]);
    return r;
}

__device__ inline s16x8 cvt8(f32x4 a, f32x4 b) {
    s16x8 r;
    r[0] = bfbits(a[0]); r[1] = bfbits(a[1]); r[2] = bfbits(a[2]); r[3] = bfbits(a[3]);
    r[4] = bfbits(b[0]); r[5] = bfbits(b[1]); r[6] = bfbits(b[2]); r[7] = bfbits(b[3]);
    return r;
}

// -------- Kernel 1: row degree + dinv + adj->bf16 in MFMA A-fragment order -----
// abf layout: [mt = m>>4][kgrp = k>>5][lane = ((k>>3)&3)*16 + (m&15)][jj = k&7]
// fp32 adj is read ONCE here, nontemporally (keep L3 for the bf16 output, which
// agg re-reads). Block = 16-row m-tile, 64 chunks of 128 k; LDS-transposed
// double-buffered writes -> contiguous 1 KB/wave global stores.
__global__ __launch_bounds__(256) void deg_kernel(const float* __restrict__ adj,
                                                  float* __restrict__ dinv,
                                                  unsigned short* __restrict__ abf) {
    __shared__ short lds[2][2048];
    const int t  = threadIdx.x;
    const int m0 = blockIdx.x << 4;
    const int r0 = t >> 5;          // row 0..7
    const int r1 = r0 + 8;
    const int c  = (t & 31) << 2;   // float offset within 128-chunk
    const int kgl = c >> 5;
    const int q   = (c >> 3) & 3;
    const int jj  = c & 7;
    const int so0 = kgl * 512 + ((q << 4) + r0) * 8 + jj;
    const int so1 = kgl * 512 + ((q << 4) + r1) * 8 + jj;

    const float* ap0 = adj + (size_t)(m0 + r0) * NN + c;
    const float* ap1 = adj + (size_t)(m0 + r1) * NN + c;
    unsigned short* wp = abf + (((size_t)blockIdx.x * 256 + (t >> 6)) * 64 + (t & 63)) * 8;

    f32x4 s0 = {0.f, 0.f, 0.f, 0.f};
    f32x4 s1 = {0.f, 0.f, 0.f, 0.f};

    f32x4 v0 = ntload((const f32x4*)ap0);
    f32x4 v1 = ntload((const f32x4*)ap1);

    for (int ch = 0; ch < 64; ++ch) {
        const int b = ch & 1;
        s0 += v0;
        s1 += v1;
        *(s16x4*)&lds[b][so0] = cvt4(v0);
        *(s16x4*)&lds[b][so1] = cvt4(v1);
        f32x4 n0, n1;
        if (ch < 63) {
            n0 = ntload((const f32x4*)(ap0 + (ch + 1) * 128));
            n1 = ntload((const f32x4*)(ap1 + (ch + 1) * 128));
        }
        __syncthreads();
        s16x8 wv = *(const s16x8*)&lds[b][t * 8];
        *(s16x8*)(wp + (size_t)ch * 2048) = wv;   // 4 kgrps * 512 shorts per chunk
        v0 = n0;
        v1 = n1;
    }

    // row sums: 32 consecutive threads (one 32-lane half) share each row
    float a0 = s0[0] + s0[1] + s0[2] + s0[3];
    float a1 = s1[0] + s1[1] + s1[2] + s1[3];
    #pragma unroll
    for (int off = 16; off; off >>= 1) {
        a0 += __shfl_xor(a0, off, 64);
        a1 += __shfl_xor(a1, off, 64);
    }
    if ((t & 31) == 0) {
        dinv[m0 + r0] = (a0 > 0.f) ? rsqrtf(a0) : 0.f;
        dinv[m0 + r1] = (a1 > 0.f) ? rsqrtf(a1) : 0.f;
    }
}

// -------- Kernel 2: h2f = dinv[j]*(x@W)[j][n] stored in MFMA B-fragment order ----
// h2f: [f = n>>4][kgrp = j>>5][lane = ((j>>3)&3)*16 + (n&15)][jj = j&7]
#define WST 132
__global__ __launch_bounds__(256) void proj_kernel(const float* __restrict__ x,
                                                   const float* __restrict__ w,
                                                   const float* __restrict__ dinv,
                                                   unsigned short* __restrict__ h2f) {
    __shared__ short lds_w[128 * WST];
    const int tid  = threadIdx.x;
    const int lane = tid & 63;
    const int wave = tid >> 6;
    const int j0   = blockIdx.x << 4;
    const int n0   = wave << 5;
    const int r    = lane & 15;
    const int q    = lane >> 4;

    #pragma unroll
    for (int i = 0; i < 16; ++i) {
        int gi = i * 256 + tid;
        int k  = gi >> 5;
        int n4 = (gi & 31) << 2;
        f32x4 v = *(const f32x4*)(w + (size_t)k * DD + n4);
        *(s16x4*)&lds_w[k * WST + n4] = cvt4(v);
    }
    __syncthreads();

    const float* xp = x + (size_t)(j0 + r) * DD + (q << 3);

    f32x4 acc0 = {0.f, 0.f, 0.f, 0.f};
    f32x4 acc1 = {0.f, 0.f, 0.f, 0.f};

    #pragma unroll
    for (int k = 0; k < DD; k += 32) {
        f32x4 a0 = *(const f32x4*)(xp + k);
        f32x4 a1 = *(const f32x4*)(xp + k + 4);
        s16x8 af = cvt8(a0, a1);

        const int kb = k + (q << 3);
        s16x8 b0, b1;
        #pragma unroll
        for (int jj = 0; jj < 8; ++jj) {
            b0[jj] = lds_w[(kb + jj) * WST + n0 + r];
            b1[jj] = lds_w[(kb + jj) * WST + n0 + 16 + r];
        }
        acc0 = __builtin_amdgcn_mfma_f32_16x16x32_bf16(af, b0, acc0, 0, 0, 0);
        acc1 = __builtin_amdgcn_mfma_f32_16x16x32_bf16(af, b1, acc1, 0, 0, 0);
    }

    #pragma unroll
    for (int rr = 0; rr < 4; ++rr) {
        const int j = j0 + (q << 2) + rr;
        const float dv = dinv[j];
        const int kg = j >> 5, qp = (j >> 3) & 3, jjj = j & 7;
        #pragma unroll
        for (int half = 0; half < 2; ++half) {
            const int n = n0 + half * 16 + r;
            const int f = n >> 4;
            const int lanep = qp * 16 + (n & 15);
            const float v = (half ? acc1[rr] : acc0[rr]) * dv;
            h2f[(((size_t)f * 256 + kg) * 64 + lanep) * 8 + jjj] = (unsigned short)bfbits(v);
        }
    }
}

// -------- Kernel 3: LDS-free streaming MFMA aggregation ------------------------
// m-tile 32 (two abf 16-tiles), wave = 2 n-frags; per kgrp: 2 A + 2 B 16B loads,
// 4 MFMAs. No barriers. Reverse m order so freshest abf (written last by deg)
// is read first (L3 residency).
template <int KSPLIT>
__global__ __launch_bounds__(256, 4) void agg_kernel(const unsigned short* __restrict__ abf,
                                                     const unsigned short* __restrict__ h2f,
                                                     const float* __restrict__ dinv,
                                                     const float* __restrict__ bias,
                                                     float* __restrict__ dst) {
    constexpr int KGS = (NN / KSPLIT) >> 5;   // kgrps per block
    const int lane = threadIdx.x & 63;
    const int wave = threadIdx.x >> 6;
    const int r    = lane & 15;
    const int q    = lane >> 4;
    const int mt   = (int)(gridDim.x - 1 - blockIdx.x);  // reverse order
    const int m0   = mt << 5;
    const int kg0  = blockIdx.y * KGS;
    const int f0   = wave << 1;

    const unsigned short* a0 = abf + (((size_t)(mt * 2)     * 256 + kg0) * 64 + lane) * 8;
    const unsigned short* a1 = abf + (((size_t)(mt * 2 + 1) * 256 + kg0) * 64 + lane) * 8;
    const unsigned short* b0 = h2f + (((size_t)f0       * 256 + kg0) * 64 + lane) * 8;
    const unsigned short* b1 = h2f + (((size_t)(f0 + 1) * 256 + kg0) * 64 + lane) * 8;

    f32x4 acc00 = {0.f, 0.f, 0.f, 0.f};
    f32x4 acc01 = {0.f, 0.f, 0.f, 0.f};
    f32x4 acc10 = {0.f, 0.f, 0.f, 0.f};
    f32x4 acc11 = {0.f, 0.f, 0.f, 0.f};

    #pragma unroll 8
    for (int kg = 0; kg < KGS; ++kg) {
        s16x8 va0 = ntload((const s16x8*)(a0 + (size_t)kg * 512));
        s16x8 va1 = ntload((const s16x8*)(a1 + (size_t)kg * 512));
        s16x8 vb0 = *(const s16x8*)(b0 + (size_t)kg * 512);
        s16x8 vb1 = *(const s16x8*)(b1 + (size_t)kg * 512);
        acc00 = __builtin_amdgcn_mfma_f32_16x16x32_bf16(va0, vb0, acc00, 0, 0, 0);
        acc01 = __builtin_amdgcn_mfma_f32_16x16x32_bf16(va0, vb1, acc01, 0, 0, 0);
        acc10 = __builtin_amdgcn_mfma_f32_16x16x32_bf16(va1, vb0, acc10, 0, 0, 0);
        acc11 = __builtin_amdgcn_mfma_f32_16x16x32_bf16(va1, vb1, acc11, 0, 0, 0);
    }

    // C/D: col = lane&15 (n), row = q*4+rr (m within 16-tile)
    const int n = (wave << 5) + r;
    #pragma unroll
    for (int rr = 0; rr < 4; ++rr) {
        const int ma = m0 + (q << 2) + rr;
        const int mb = ma + 16;
        if (KSPLIT == 1) {
            const float dva = dinv[ma], dvb = dinv[mb];
            dst[(size_t)ma * DD + n]      = acc00[rr] * dva + bias[n];
            dst[(size_t)ma * DD + n + 16] = acc01[rr] * dva + bias[n + 16];
            dst[(size_t)mb * DD + n]      = acc10[rr] * dvb + bias[n];
            dst[(size_t)mb * DD + n + 16] = acc11[rr] * dvb + bias[n + 16];
        } else {
            float* p = dst + (size_t)blockIdx.y * NN * DD;
            p[(size_t)ma * DD + n]      = acc00[rr];
            p[(size_t)ma * DD + n + 16] = acc01[rr];
            p[(size_t)mb * DD + n]      = acc10[rr];
            p[(size_t)mb * DD + n + 16] = acc11[rr];
        }
    }
}

// -------- Kernel 4: out = dinv[m]*(sum of partials) + bias --------
template <int KSPLIT>
__global__ __launch_bounds__(256) void reduce_kernel(const float* __restrict__ part,
                                                     const float* __restrict__ dinv,
                                                     const float* __restrict__ bias,
                                                     float* __restrict__ out) {
    const int idx = blockIdx.x * 256 + threadIdx.x;
    f32x4 s = ntload((const f32x4*)part + idx);
    #pragma unroll
    for (int p = 1; p < KSPLIT; ++p)
        s += ntload((const f32x4*)part + idx + (size_t)p * (NN * DD / 4));
    const float dv = dinv[idx >> 5];
    const f32x4 bi = *(const f32x4*)(bias + ((idx & 31) << 2));
    f32x4 o;
    o[0] = s[0] * dv + bi[0]; o[1] = s[1] * dv + bi[1];
    o[2] = s[2] * dv + bi[2]; o[3] = s[3] * dv + bi[3];
    ((f32x4*)out)[idx] = o;
}

extern "C" void kernel_launch(void* const* d_in, const int* in_sizes, int n_in,
                              void* d_out, int out_size, void* d_ws, size_t ws_size,
                              hipStream_t stream) {
    const float* x    = (const float*)d_in[0];   // [8192][128]
    const float* adj  = (const float*)d_in[1];   // [8192][8192]
    const float* w    = (const float*)d_in[2];   // [128][128]
    const float* bias = (const float*)d_in[3];   // [128]
    float* out = (float*)d_out;                  // [8192][128]

    // ws: dinv 32 KB | h2f 2 MB | abf 128 MB | partials KSPLIT x 4 MB
    float* dinv = (float*)d_ws;
    unsigned short* h2f = (unsigned short*)((char*)d_ws + 32 * 1024);
    unsigned short* abf = (unsigned short*)((char*)d_ws + 32 * 1024 + 2 * 1024 * 1024);
    float* part = (float*)((char*)d_ws + 32 * 1024 + 2 * 1024 * 1024 + (size_t)NN * NN * 2);

    const size_t base  = 32 * 1024 + 2 * 1024 * 1024 + (size_t)NN * NN * 2;
    const size_t need4 = base + (size_t)4 * NN * DD * sizeof(float);
    const size_t need1 = base;

    deg_kernel<<<NN / 16, 256, 0, stream>>>(adj, dinv, abf);
    proj_kernel<<<NN / 16, 256, 0, stream>>>(x, w, dinv, h2f);

    if (ws_size >= need4) {
        agg_kernel<4><<<dim3(NN / 32, 4), 256, 0, stream>>>(abf, h2f, dinv, bias, part);
        reduce_kernel<4><<<NN * DD / 4 / 256, 256, 0, stream>>>(part, dinv, bias, out);
    } else if (ws_size >= need1) {
        agg_kernel<1><<<dim3(NN / 32, 1), 256, 0, stream>>>(abf, h2f, dinv, bias, out);
    }
}